// Round 5
// baseline (572.000 us; speedup 1.0000x reference)
//
#include <hip/hip_runtime.h>
#include <math.h>

namespace {
constexpr int kB    = 32;
constexpr int kMel  = 128;
constexpr int kT    = 8192;
constexpr int kKeys = 88;
constexpr int kTop  = 15;   // top[13] = 14th largest, top[14] = 15th largest

// key_bins is DETERMINISTIC (derived from the mel formula, no RNG).
// Verified at runtime against d_in[1]; mismatch -> generic cold path.
__device__ constexpr int kBins[kKeys] = {
   1,  1,  1,  1,  1,  2,  2,  2,  2,  2,  2,  2,  2,  2,  3,  3,
   3,  3,  3,  3,  4,  4,  4,  4,  5,  5,  5,  6,  6,  6,  7,  7,
   7,  8,  8,  9,  9, 10, 10, 11, 12, 12, 13, 14, 15, 16, 17, 17,
  19, 20, 21, 22, 23, 25, 26, 28, 29, 31, 33, 35, 37, 39, 42, 44,
  46, 49, 51, 53, 56, 58, 60, 63, 65, 68, 70, 72, 75, 77, 79, 82,
  84, 86, 89, 91, 93, 96, 98, 101};
}

__device__ __forceinline__ void top_insert(float (&top)[kTop], float v) {
#pragma unroll
  for (int j = 0; j < kTop; ++j) {
    const float hi = fmaxf(top[j], v);
    v = fminf(top[j], v);
    top[j] = hi;
  }
}

// waves_per_eu(3,4): forbid the allocator's occupancy-greedy 8-waves/EU target
// (R2 evidence: it chose 64 VGPR + scratch spill). Budget >=128 regs keeps
// s[~57 unique]+top[15]+temps entirely in registers. 12-16 waves/CU.
__global__ __attribute__((amdgpu_waves_per_eu(3, 4))) __launch_bounds__(256)
void key_probs_kernel(const float* __restrict__ mel,
                      const int* __restrict__ key_bins,
                      float* __restrict__ out) {
  __shared__ int sbins[kKeys];
  __shared__ int smismatch;
  const int tid = threadIdx.x;
  if (tid == 0) smismatch = 0;
  __syncthreads();
  if (tid < kKeys) {
    const int m = key_bins[tid];
    sbins[tid] = m;
    if (m != kBins[tid]) atomicOr(&smismatch, 1);
  }
  __syncthreads();
  const bool generic = (smismatch != 0);

  const int t = blockIdx.x * 256 + tid;
  const int b = blockIdx.y;
  const float* mb = mel + (size_t)b * (kMel * kT);
  float* o0 = out + (size_t)b * kKeys * kT + t;
  float* o1 = o0 + (size_t)kB * kKeys * kT;

  // ---- single gather pass: sums held in registers, streaming top-15 -------
  // e = exp(a)exp(b)exp(c) is monotone in s = a+b+c: rank entirely on sums.
  // Duplicate bins CSE to one register each (constant indices throughout).
  float s[kKeys];
  float top[kTop];
#pragma unroll
  for (int j = 0; j < kTop; ++j) top[j] = -1e30f;
  if (!generic) {
#pragma unroll
    for (int k = 0; k < kKeys; ++k) {
      const int m = kBins[k];  // compile-time constant
      float v = mb[(size_t)m * kT + t];
      if (m < 64) v += mb[(size_t)(2 * m) * kT + t];
      if (m < 43) v += mb[(size_t)(3 * m) * kT + t];
      s[k] = v;
      top_insert(top, v);
    }
  }

  const float r74 = top[13];
  // Only the rank-14/15 boundary matters: swaps internal to the top-14 set
  // (or entirely below) can't change the mask. Sum-space gap < ~2.5e-6 is
  // where the reference's product-space rounding could flip the boundary.
  const bool amb = generic || ((top[13] - top[14]) < 1e-5f);

  if (amb) {
    // COLD path (rare lanes / bins-mismatch): product space, runtime bins,
    // np-compatible correctly-rounded fp32 exp. Rolled loops, and it never
    // touches s[] (a dynamic s[k] write would force s[] to scratch).
    float tp[kTop];
#pragma unroll
    for (int j = 0; j < kTop; ++j) tp[j] = 0.0f;  // products are positive
#pragma unroll 1
    for (int k = 0; k < kKeys; ++k) {
      const int m = __builtin_amdgcn_readfirstlane(sbins[k]);
      float v = (float)::exp((double)mb[(size_t)m * kT + t]);
      if (m < 64) v *= (float)::exp((double)mb[(size_t)(2 * m) * kT + t]);
      if (m < 43) v *= (float)::exp((double)mb[(size_t)(3 * m) * kT + t]);
      top_insert(tp, v);
    }
    const float r74p = tp[13];
#pragma unroll 1
    for (int k = 0; k < kKeys; ++k) {
      const int m = __builtin_amdgcn_readfirstlane(sbins[k]);
      float v = (float)::exp((double)mb[(size_t)m * kT + t]);
      if (m < 64) v *= (float)::exp((double)mb[(size_t)(2 * m) * kT + t]);
      if (m < 43) v *= (float)::exp((double)mb[(size_t)(3 * m) * kT + t]);
      const float r = (v >= r74p) ? 1.0f : 0.0f;
      o0[(size_t)k * kT] = r;
      o1[(size_t)k * kT] = r;
    }
  }

  if (!amb) {
    // HOT classify: straight from registers. Plain stores (nontemporal
    // doubled WRITE_SIZE to 356 MB in R4 - partial-line HBM writes).
#pragma unroll
    for (int k = 0; k < kKeys; ++k) {
      const float r = (s[k] >= r74) ? 1.0f : 0.0f;
      o0[(size_t)k * kT] = r;
      o1[(size_t)k * kT] = r;
    }
  }
}

extern "C" void kernel_launch(void* const* d_in, const int* in_sizes, int n_in,
                              void* d_out, int out_size, void* d_ws, size_t ws_size,
                              hipStream_t stream) {
  const float* mel = (const float*)d_in[0];
  const int* key_bins = (const int*)d_in[1];
  float* out = (float*)d_out;
  dim3 grid(kT / 256, kB);
  key_probs_kernel<<<grid, dim3(256), 0, stream>>>(mel, key_bins, out);
}

// Round 6
// 486.584 us; speedup vs baseline: 1.1755x; 1.1755x over previous
//
#include <hip/hip_runtime.h>
#include <math.h>
#include <stdint.h>

namespace {
constexpr int kB    = 32;
constexpr int kMel  = 128;
constexpr int kT    = 8192;
constexpr int kKeys = 88;
constexpr int kTop  = 15;   // top[13] = 14th largest, top[14] = 15th largest

// key_bins is DETERMINISTIC (derived from the mel formula, no RNG).
// Verified at runtime against d_in[1]; mismatch -> generic cold path.
constexpr int kBinsH[kKeys] = {
   1,  1,  1,  1,  1,  2,  2,  2,  2,  2,  2,  2,  2,  2,  3,  3,
   3,  3,  3,  3,  4,  4,  4,  4,  5,  5,  5,  6,  6,  6,  7,  7,
   7,  8,  8,  9,  9, 10, 10, 11, 12, 12, 13, 14, 15, 16, 17, 17,
  19, 20, 21, 22, 23, 25, 26, 28, 29, 31, 33, 35, 37, 39, 42, 44,
  46, 49, 51, 53, 56, 58, 60, 63, 65, 68, 70, 72, 75, 77, 79, 82,
  84, 86, 89, 91, 93, 96, 98, 101};

constexpr int kNU = 57;  // unique bins (duplicates share one register)
struct BinMap { int uniq[kNU]; int uidx[kKeys]; };
constexpr BinMap make_map() {
  BinMap m{}; int n = 0;
  for (int k = 0; k < kKeys; ++k) {
    int f = -1;
    for (int j = 0; j < n; ++j) if (m.uniq[j] == kBinsH[k]) { f = j; break; }
    if (f < 0) { m.uniq[n] = kBinsH[k]; f = n++; }
    m.uidx[k] = f;
  }
  return m;
}
constexpr BinMap kMap = make_map();
}

__device__ __forceinline__ void top_insert(float (&top)[kTop], float v) {
#pragma unroll
  for (int j = 0; j < kTop; ++j) {
    const float hi = fmaxf(top[j], v);
    v = fminf(top[j], v);
    top[j] = hi;
  }
}

// K1: per column compute 57 unique log-domain sums, select rank-14/15,
// emit an 88-bit mask (one uint4 = 16 B) to workspace. Writes only 4 MB
// total -> no cache pollution, no need to re-read mel, no s[88] spill.
// launch_bounds min-waves=1: allocator budget up to 512 VGPR, uses ~what
// it needs (~85-160) instead of squeezing to 64 and spilling (R2/R5).
template <bool DIRECT>
__global__ __launch_bounds__(256, 1) void thresh_kernel(
    const float* __restrict__ mel, const int* __restrict__ key_bins,
    uint4* __restrict__ mask, float* __restrict__ out) {
  __shared__ int sbins[kKeys];
  __shared__ int smis;
  const int tid = threadIdx.x;
  if (tid == 0) smis = 0;
  __syncthreads();
  if (tid < kKeys) {
    const int m = key_bins[tid];
    sbins[tid] = m;
    if (m != kBinsH[tid]) atomicOr(&smis, 1);
  }
  __syncthreads();
  const bool generic = (smis != 0);

  const int t = blockIdx.x * 256 + tid;
  const int b = blockIdx.y;
  const float* mb = mel + (size_t)b * (kMel * kT);

  // unique sums (constexpr rows, all <=126 < 128: always in-bounds)
  float u[kNU];
#pragma unroll
  for (int q = 0; q < kNU; ++q) {
    const int m = kMap.uniq[q];
    float v = mb[(size_t)m * kT + t];
    if (m < 64) v += mb[(size_t)(2 * m) * kT + t];
    if (m < 43) v += mb[(size_t)(3 * m) * kT + t];
    u[q] = v;
  }

  // streaming top-15 over the 88 keys (duplicates re-insert the same reg)
  float top[kTop];
#pragma unroll
  for (int j = 0; j < kTop; ++j) top[j] = -1e30f;
#pragma unroll
  for (int k = 0; k < kKeys; ++k) top_insert(top, u[kMap.uidx[k]]);

  const float r74 = top[13];
  // Only the rank-14/15 boundary gap matters; sum-space gap < 1e-5 covers
  // the product-space rounding disagreement band (~1.5e-6) with margin.
  const bool amb = generic || ((top[13] - top[14]) < 1e-5f);

  uint32_t w0 = 0, w1 = 0, w2 = 0;
#pragma unroll
  for (int k = 0; k < kKeys; ++k) {
    const uint32_t bit = (u[kMap.uidx[k]] >= r74) ? 1u : 0u;
    if (k < 32)      w0 |= bit << k;
    else if (k < 64) w1 |= bit << (k - 32);
    else             w2 |= bit << (k - 64);
  }

  if (amb) {
    // COLD (rare lanes / bins-mismatch): product space, runtime bins,
    // np-compatible correctly-rounded fp32 exp. Rolled -> tiny code.
    float tp[kTop];
#pragma unroll
    for (int j = 0; j < kTop; ++j) tp[j] = 0.0f;  // products are positive
#pragma unroll 1
    for (int k = 0; k < kKeys; ++k) {
      const int m = __builtin_amdgcn_readfirstlane(sbins[k]);
      float v = (float)::exp((double)mb[(size_t)m * kT + t]);
      if (m < 64) v *= (float)::exp((double)mb[(size_t)(2 * m) * kT + t]);
      if (m < 43) v *= (float)::exp((double)mb[(size_t)(3 * m) * kT + t]);
      top_insert(tp, v);
    }
    const float r74p = tp[13];
    w0 = 0; w1 = 0; w2 = 0;
#pragma unroll 1
    for (int k = 0; k < kKeys; ++k) {
      const int m = __builtin_amdgcn_readfirstlane(sbins[k]);
      float v = (float)::exp((double)mb[(size_t)m * kT + t]);
      if (m < 64) v *= (float)::exp((double)mb[(size_t)(2 * m) * kT + t]);
      if (m < 43) v *= (float)::exp((double)mb[(size_t)(3 * m) * kT + t]);
      const uint32_t sh = ((v >= r74p) ? 1u : 0u) << (k & 31);
      w0 |= (k < 32) ? sh : 0u;
      w1 |= (k >= 32 && k < 64) ? sh : 0u;
      w2 |= (k >= 64) ? sh : 0u;
    }
  }

  if (DIRECT) {  // fallback when ws too small: write floats directly
    float* o0 = out + (size_t)b * kKeys * kT + t;
    float* o1 = o0 + (size_t)kB * kKeys * kT;
#pragma unroll
    for (int k = 0; k < kKeys; ++k) {
      const uint32_t w = (k < 32) ? w0 : ((k < 64) ? w1 : w2);
      const float r = (float)((w >> (k & 31)) & 1u);
      o0[(size_t)k * kT] = r;
      o1[(size_t)k * kT] = r;
    }
  } else {
    mask[(size_t)b * kT + t] = make_uint4(w0, w1, w2, 0u);
  }
}

// K2: expand 88-bit masks to the two float outputs. Each thread holds the
// masks of 4 columns in registers and reuses them across an 11-key chunk.
// Pure write-stream: float4 stores, 1 KB contiguous per wave per store.
__global__ __launch_bounds__(256) void expand_kernel(
    const uint4* __restrict__ mask, float* __restrict__ out) {
  const int tid = threadIdx.x;
  const int b = blockIdx.y;
  const int t4 = blockIdx.x * 1024 + tid * 4;
  const uint4* mp = mask + (size_t)b * kT + t4;
  const uint4 m0 = mp[0], m1 = mp[1], m2 = mp[2], m3 = mp[3];
  const int kc = blockIdx.z * 11;
  float* o0 = out + ((size_t)b * kKeys + kc) * kT + t4;
  float* o1 = o0 + (size_t)kB * kKeys * kT;
#pragma unroll
  for (int kk = 0; kk < 11; ++kk) {
    const int k = kc + kk;          // wave-uniform (scalar j, sh)
    const int j = k >> 5, sh = k & 31;
    const uint32_t a0 = (j == 0) ? m0.x : ((j == 1) ? m0.y : m0.z);
    const uint32_t a1 = (j == 0) ? m1.x : ((j == 1) ? m1.y : m1.z);
    const uint32_t a2 = (j == 0) ? m2.x : ((j == 1) ? m2.y : m2.z);
    const uint32_t a3 = (j == 0) ? m3.x : ((j == 1) ? m3.y : m3.z);
    float4 r;
    r.x = (float)((a0 >> sh) & 1u);
    r.y = (float)((a1 >> sh) & 1u);
    r.z = (float)((a2 >> sh) & 1u);
    r.w = (float)((a3 >> sh) & 1u);
    *(float4*)(o0 + (size_t)kk * kT) = r;
    *(float4*)(o1 + (size_t)kk * kT) = r;
  }
}

extern "C" void kernel_launch(void* const* d_in, const int* in_sizes, int n_in,
                              void* d_out, int out_size, void* d_ws, size_t ws_size,
                              hipStream_t stream) {
  const float* mel = (const float*)d_in[0];
  const int* key_bins = (const int*)d_in[1];
  float* out = (float*)d_out;
  const size_t need = (size_t)kB * kT * sizeof(uint4);  // 4 MiB
  if (ws_size >= need) {
    uint4* mask = (uint4*)d_ws;
    thresh_kernel<false><<<dim3(kT / 256, kB), 256, 0, stream>>>(mel, key_bins, mask, nullptr);
    expand_kernel<<<dim3(kT / 1024, kB, 8), 256, 0, stream>>>(mask, out);
  } else {
    thresh_kernel<true><<<dim3(kT / 256, kB), 256, 0, stream>>>(mel, key_bins, nullptr, out);
  }
}